// Round 1
// baseline (14.683 us; speedup 1.0000x reference)
//
#include <hip/hip_runtime.h>
#include <math.h>

// 4-qubit statevector sim, B independent elements.
// State index t = i*8 + j*4 + k*2 + l  (qubit0=i .. qubit3=l).
// Constant prelude (RX(1),RY(1),RZ(1),CNOT01,CNOT12,CZ03 on uniform 0.25 state)
// involves only literals -> compiler constant-folds it to 32 float constants.
// Final RZ(pi/2) on qubit2 is a pure per-amplitude phase -> |psi|^2 invariant -> skipped.
__global__ __launch_bounds__(256) void qlayer_kernel(
    const float* __restrict__ in, float* __restrict__ out, int B)
{
    int b = blockIdx.x * blockDim.x + threadIdx.x;
    if (b >= B) return;

    const float w0 = in[5 * b + 3];
    const float w1 = in[5 * b + 4];

    float sr[16], si[16];
#pragma unroll
    for (int t = 0; t < 16; ++t) { sr[t] = 0.25f; si[t] = 0.0f; }

    const float ch = 0.8775825618903728f;  // cos(0.5)
    const float sh = 0.4794255386042030f;  // sin(0.5)

    // RX(1) on qubit0: [[c, -i s],[-i s, c]] on pairs (t, t+8)
#pragma unroll
    for (int r = 0; r < 8; ++r) {
        float ar = sr[r], ai = si[r], br = sr[r + 8], bi = si[r + 8];
        sr[r]     = ch * ar + sh * bi;  si[r]     = ch * ai - sh * br;
        sr[r + 8] = ch * br + sh * ai;  si[r + 8] = ch * bi - sh * ar;
    }
    // RY(1) on qubit1: [[c, -s],[s, c]] on pairs (base, base+4)
#pragma unroll
    for (int i = 0; i < 2; ++i)
#pragma unroll
        for (int m = 0; m < 4; ++m) {
            int a = i * 8 + m, c = a + 4;
            float ar = sr[a], ai = si[a], br = sr[c], bi = si[c];
            sr[a] = ch * ar - sh * br;  si[a] = ch * ai - sh * bi;
            sr[c] = sh * ar + ch * br;  si[c] = sh * ai + ch * bi;
        }
    // RZ(1) on qubit2: k=0 -> *(ch - i sh); k=1 -> *(ch + i sh)
#pragma unroll
    for (int t = 0; t < 16; ++t) {
        float re = sr[t], im = si[t];
        if ((t & 2) == 0) { sr[t] = ch * re + sh * im; si[t] = ch * im - sh * re; }
        else              { sr[t] = ch * re - sh * im; si[t] = ch * im + sh * re; }
    }
    // CNOT(q0->q1): new[1,j,k,l] = old[1,1-j,k,l]  -> swap (8+m)<->(12+m)
#pragma unroll
    for (int m = 0; m < 4; ++m) {
        float tr = sr[8 + m]; sr[8 + m] = sr[12 + m]; sr[12 + m] = tr;
        float ti = si[8 + m]; si[8 + m] = si[12 + m]; si[12 + m] = ti;
    }
    // CNOT(q1->q2): new[i,1,k,l] = old[i,1,1-k,l] -> swap (i*8+4+l)<->(i*8+6+l)
#pragma unroll
    for (int i = 0; i < 2; ++i)
#pragma unroll
        for (int l = 0; l < 2; ++l) {
            int a = i * 8 + 4 + l, c = i * 8 + 6 + l;
            float tr = sr[a]; sr[a] = sr[c]; sr[c] = tr;
            float ti = si[a]; si[a] = si[c]; si[c] = ti;
        }
    // CZ(q0,q3): negate amplitudes with i=1, l=1 -> t in {9,11,13,15}
#pragma unroll
    for (int t = 9; t < 16; t += 2) { sr[t] = -sr[t]; si[t] = -si[t]; }

    // Data-dependent rotations. Gate angle is theta = pi/2*(1+w); matrices use theta/2.
    const float qpi = 0.7853981633974483f;  // pi/4
    float s0, c0, s1, c1;
    sincosf(qpi * (1.0f + w0), &s0, &c0);
    sincosf(qpi * (1.0f + w1), &s1, &c1);

    // RX(t0) on qubit0
#pragma unroll
    for (int r = 0; r < 8; ++r) {
        float ar = sr[r], ai = si[r], br = sr[r + 8], bi = si[r + 8];
        sr[r]     = c0 * ar + s0 * bi;  si[r]     = c0 * ai - s0 * br;
        sr[r + 8] = c0 * br + s0 * ai;  si[r + 8] = c0 * bi - s0 * ar;
    }
    // RY(t1) on qubit1
#pragma unroll
    for (int i = 0; i < 2; ++i)
#pragma unroll
        for (int m = 0; m < 4; ++m) {
            int a = i * 8 + m, c = a + 4;
            float ar = sr[a], ai = si[a], br = sr[c], bi = si[c];
            sr[a] = c1 * ar - s1 * br;  si[a] = c1 * ai - s1 * bi;
            sr[c] = s1 * ar + c1 * br;  si[c] = s1 * ai + c1 * bi;
        }
    // (RZ(pi/2) on qubit2 skipped: phase-only, |amp|^2 unchanged.)

    // Probabilities and Z expectations per qubit.
    float e0 = 0.f, e1 = 0.f, e2 = 0.f, e3 = 0.f;
#pragma unroll
    for (int t = 0; t < 16; ++t) {
        float p = sr[t] * sr[t] + si[t] * si[t];
        e0 += (t & 8) ? -p : p;
        e1 += (t & 4) ? -p : p;
        e2 += (t & 2) ? -p : p;
        e3 += (t & 1) ? -p : p;
    }

    float4 o = make_float4(e0, e1, e2, e3);
    reinterpret_cast<float4*>(out)[b] = o;
}

extern "C" void kernel_launch(void* const* d_in, const int* in_sizes, int n_in,
                              void* d_out, int out_size, void* d_ws, size_t ws_size,
                              hipStream_t stream) {
    const float* in = (const float*)d_in[0];
    float* out = (float*)d_out;
    const int B = in_sizes[0] / 5;  // (B, 5) float32
    const int block = 256;
    const int grid = (B + block - 1) / block;
    qlayer_kernel<<<grid, block, 0, stream>>>(in, out, B);
}

// Round 2
// 10.433 us; speedup vs baseline: 1.4074x; 1.4074x over previous
//
#include <hip/hip_runtime.h>
#include <math.h>

// Closed form of the 4-qubit circuit (derived in Heisenberg picture, verified
// against the full-statevector kernel which passed in R1):
//   pre-final state: amp(i,j,k,l) = 1/4 * (-1)^{i*l} * a_{i^j} * b_{j^k},
//     a0,a1 = cos(1/2) -/+ sin(1/2),  b_{0,1} = exp(-/+ i/2)
//   e0 = cos(a)<Z_i> + sin(a)<Y_i> = 0   (both terms vanish; w0 drops out)
//   e1 = cos(b)<Z_j> - sin(b)<X_j> = -cos^2(1) * cos(pi*w1/2)
//   e2 = <Z_k> = 0   (RZ(pi/2) commutes with Z; |amp|^2 indep of k)
//   e3 = <Z_l> = 0   (|amp|^2 indep of l)
__global__ __launch_bounds__(256) void qlayer_kernel(
    const float* __restrict__ in, float* __restrict__ out, int B)
{
    int b = blockIdx.x * blockDim.x + threadIdx.x;
    if (b >= B) return;

    const float w1 = in[5 * b + 4];
    // cos(pi/2 * w1) via fast intrinsic (w1 in [0,1) -> no range reduction issues)
    const float c = __cosf(1.5707963267948966f * w1);
    const float e1 = -0.2919265817264289f * c;  // -cos^2(1) * c

    reinterpret_cast<float4*>(out)[b] = make_float4(0.0f, e1, 0.0f, 0.0f);
}

extern "C" void kernel_launch(void* const* d_in, const int* in_sizes, int n_in,
                              void* d_out, int out_size, void* d_ws, size_t ws_size,
                              hipStream_t stream) {
    const float* in = (const float*)d_in[0];
    float* out = (float*)d_out;
    const int B = in_sizes[0] / 5;  // (B, 5) float32
    const int block = 256;
    const int grid = (B + block - 1) / block;
    qlayer_kernel<<<grid, block, 0, stream>>>(in, out, B);
}